// Round 1
// baseline (185.101 us; speedup 1.0000x reference)
//
#include <hip/hip_runtime.h>
#include <hip/hip_bf16.h>

#define NNODES 100000
#define NEDGES 1600000
#define IN_DIM 64
#define HID_DIM 128

#define BUKSHIFT 8                   // 256 nodes per bucket (best measured geometry)
#define BUKNODES 256
#define NBUK ((NNODES + 255) >> 8)   // 391 buckets
#define BUKCAP 4608                  // mean 4094 + 8 sigma; deterministic input -> safe
#define CHUNK 4096                   // edges per partition block
#define TILE_N 128                   // nodes per fused gather+mlp block
#define W1TS 72                      // W1t row stride (bf16): 64 + 8 pad -> lane banks spread
#define SA_STRIDE 9                  // sA row stride in uint4 (144 B): banks (col*36+q*4)%32
                                     // balanced; 128 B stride would hit banks 0-15 only (2x)

// Edge packing: src in bits 0..23, dst-within-bucket (8 bits) in 24..31.
#define EPACK(s, d)  ((s) | (((d) & 255) << 24))
#define ESRC(p)      ((p) & 0x00FFFFFF)
#define EDL(p)       ((int)(((unsigned)(p)) >> 24))

typedef __attribute__((ext_vector_type(8))) short short8;   // 8 bf16 = 4 VGPRs
typedef __attribute__((ext_vector_type(4))) float f32x4;

// bf16 helpers (RNE round; unpack = shift/mask only)
__device__ inline unsigned short f2bf(float f) {
    unsigned u = __float_as_uint(f);
    u += 0x7fff + ((u >> 16) & 1);
    return (unsigned short)(u >> 16);
}
__device__ inline unsigned bfpack2(float a, float b) {
    return (unsigned)f2bf(a) | ((unsigned)f2bf(b) << 16);
}
__device__ inline float bflo(unsigned u) { return __uint_as_float(u << 16); }
__device__ inline float bfhi(unsigned u) { return __uint_as_float(u & 0xffff0000u); }

// ---------- phase 1: bucket-partition edges into packed ebuf ----------
__global__ __launch_bounds__(1024, 8) void k_part(const int* __restrict__ src,
                                                  const int* __restrict__ dst,
                                                  int* __restrict__ gbcur,
                                                  int* __restrict__ ebuf, int E) {
    __shared__ int stage[CHUNK];               // 16 KB packed edges
    __shared__ unsigned short bukof[CHUNK];    // 8 KB bucket id per slot
    __shared__ int hist[NBUK];
    __shared__ int scanb[NBUK];
    __shared__ int basep[NBUK];
    __shared__ int sb[2][512];
    int t = threadIdx.x;
    int start = blockIdx.x * CHUNK;
    int n = E - start; if (n > CHUNK) n = CHUNK;

    if (t < NBUK) hist[t] = 0;
    __syncthreads();

    int myb[4], myr[4], mp[4];
    #pragma unroll
    for (int i = 0; i < 4; i++) {
        int c = t + i * 1024;
        if (c < n) {
            int s = src[start + c];
            int d = dst[start + c];
            int b = d >> BUKSHIFT;
            myb[i] = b;
            mp[i]  = EPACK(s, d);
            myr[i] = atomicAdd(&hist[b], 1);   // rank within (block,bucket)
        } else myb[i] = -1;
    }
    __syncthreads();

    // parallel exclusive scan of hist[NBUK] (NBUK=391 < 512)
    {
        int v = (t < NBUK) ? hist[t] : 0;
        if (t < 512) sb[0][t] = v;
        __syncthreads();
        int pin = 0;
        for (int ofs = 1; ofs < 512; ofs <<= 1) {
            if (t < 512) sb[pin ^ 1][t] = (t >= ofs) ? sb[pin][t] + sb[pin][t - ofs]
                                                     : sb[pin][t];
            __syncthreads();
            pin ^= 1;
        }
        if (t < NBUK) scanb[t] = sb[pin][t] - v;
    }

    if (t < NBUK) {                            // claim region space per bucket
        int h = hist[t];
        basep[t] = h ? (t * BUKCAP + atomicAdd(&gbcur[t], h)) : 0;
    }
    __syncthreads();

    #pragma unroll
    for (int i = 0; i < 4; i++) {              // scatter into LDS stage
        if (myb[i] >= 0) {
            int p = scanb[myb[i]] + myr[i];
            stage[p] = mp[i];
            bukof[p] = (unsigned short)myb[i];
        }
    }
    __syncthreads();

    for (int c = t; c < n; c += 1024) {        // positional writeout in runs
        int b = bukof[c];
        ebuf[basep[b] + (c - scanb[b])] = stage[c];
    }
}

// ---------- phase 2: degrees + dinv + off/end + csr fill + x->xsb convert ----
__global__ __launch_bounds__(1024, 8) void k_bfill(const int* __restrict__ gbcur,
                                                   const int* __restrict__ ebuf,
                                                   const float* __restrict__ x,
                                                   int* __restrict__ off,
                                                   int* __restrict__ nend,
                                                   float* __restrict__ dinv,
                                                   int* __restrict__ csr,
                                                   unsigned* __restrict__ xsb, int N) {
    __shared__ int sEdge[BUKCAP];              // 18.4 KB
    __shared__ int lcnt[BUKNODES];
    __shared__ int sbuf[2][BUKNODES];
    __shared__ int cur[BUKNODES];
    __shared__ float sdinv[BUKNODES];
    int b = blockIdx.x, t = threadIdx.x;
    int nbase = b << BUKSHIFT;
    int rbase = b * BUKCAP;
    int cntb = gbcur[b];                       // final bucket edge count
    if (t < BUKNODES) lcnt[t] = 0;
    __syncthreads();
    for (int i = t; i < cntb; i += 1024) {     // load + count in one pass
        int p = ebuf[rbase + i];
        sEdge[i] = p;
        atomicAdd(&lcnt[EDL(p)], 1);
    }
    __syncthreads();
    int v = (t < BUKNODES) ? lcnt[t] : 0;
    if (t < BUKNODES) sbuf[0][t] = v;
    __syncthreads();
    int pin = 0;
    for (int ofs = 1; ofs < BUKNODES; ofs <<= 1) {
        if (t < BUKNODES) sbuf[pin ^ 1][t] = (t >= ofs) ? sbuf[pin][t] + sbuf[pin][t - ofs]
                                                        : sbuf[pin][t];
        __syncthreads();
        pin ^= 1;
    }
    if (t < BUKNODES) {
        int o = rbase + sbuf[pin][t] - v;      // region base + exclusive scan
        int nid = nbase + t;
        float dv = rsqrtf((float)v + 1.0f);
        sdinv[t] = dv;
        if (nid < N) {
            off[nid]  = o;
            nend[nid] = o + v;
            dinv[nid] = dv;
        }
        cur[t] = o;
    }
    __syncthreads();
    for (int i = t; i < cntb; i += 1024) {     // fill csr from LDS
        int p = sEdge[i];
        int pos = atomicAdd(&cur[EDL(p)], 1);
        csr[pos] = ESRC(p);
    }
    // fused convert: xsb[n] = bf16(x[n] * dinv[n]) for this bucket's nodes
    for (int i = t; i < BUKNODES * 16; i += 1024) {
        int nl = i >> 4;
        int nid = nbase + nl;
        if (nid < N) {
            float dv = sdinv[nl];
            float4 vx = ((const float4*)x)[(size_t)nid * 16 + (i & 15)];
            uint2 u;
            u.x = bfpack2(vx.x * dv, vx.y * dv);
            u.y = bfpack2(vx.z * dv, vx.w * dv);
            ((uint2*)xsb)[(size_t)nid * 16 + (i & 15)] = u;
        }
    }
}

// ---------- fused layer-1: gather-aggregate + MFMA MLP, no aggb round-trip ----
// Phase A (per wave, 16 nodes sequential): agg[n] = dd*(xs[n] + sum_s xs[s]),
// packed bf16 into per-wave LDS tile sA (row = ready-made MFMA A-fragment,
// 144 B stride for bank spread). Phase B: zd = (relu(agg @ W1 + b1) @ W2)*dinv
// via 16x mfma_f32_16x16x32_bf16 exactly as the former k_mlp (A now from LDS).
// Saves the 25.6 MB aggb write+read and one launch; bf16 rounding point is
// identical to the old aggb store, so results are bit-identical.
__global__ __launch_bounds__(512, 4) void k_gmlp(const int* __restrict__ off,
                                                 const int* __restrict__ nend,
                                                 const int* __restrict__ csr,
                                                 const uint4* __restrict__ xsb,
                                                 const float* __restrict__ dinv,
                                                 const float* __restrict__ W1,
                                                 const float* __restrict__ b1,
                                                 const float* __restrict__ W2,
                                                 float* __restrict__ zd, int n_nodes) {
    __shared__ __align__(16) unsigned short sW1t[HID_DIM * W1TS];  // 18.4 KB bf16 [hid][k]
    __shared__ float sW2[HID_DIM];
    __shared__ float sb1[HID_DIM];
    __shared__ __align__(16) uint4 sA[8 * 16 * SA_STRIDE];         // 18.4 KB, 2.3 KB/wave

    int t = threadIdx.x;
    for (int i = t; i < IN_DIM * HID_DIM; i += 512) {   // W1 [k][hid] -> bf16 [hid][k]
        int k = i >> 7, hid = i & 127;
        sW1t[hid * W1TS + k] = f2bf(W1[i]);
    }
    if (t < HID_DIM) { sW2[t] = W2[t]; sb1[t] = b1[t]; }

    int w = t >> 6;                            // wave id (8 waves, 16 nodes each)
    int lane = t & 63;
    int c = lane & 7;
    int g = lane >> 3;
    int nbase = blockIdx.x * TILE_N + w * 16;

    // ---- Phase A: gather + reduce 16 nodes (identical math to old k_gather64)
    #pragma unroll 1
    for (int i = 0; i < 16; i++) {
        int n = nbase + i;                     // wave-uniform
        uint4 r = {0, 0, 0, 0};
        if (n < n_nodes) {
            int beg = off[n], fin = nend[n];
            float dd = dinv[n];
            float f0[8] = {0, 0, 0, 0, 0, 0, 0, 0};
            float f1[8] = {0, 0, 0, 0, 0, 0, 0, 0};
            if (g == 0) {                      // self term xs[n]
                uint4 u = xsb[(size_t)n * 8 + c];
                f0[0] = bflo(u.x); f0[1] = bfhi(u.x); f0[2] = bflo(u.y); f0[3] = bfhi(u.y);
                f0[4] = bflo(u.z); f0[5] = bfhi(u.z); f0[6] = bflo(u.w); f0[7] = bfhi(u.w);
            }
            for (int base = beg; base < fin; base += 64) {
                int nn = fin - base; if (nn > 64) nn = 64;
                int idx = (lane < nn) ? csr[base + lane] : 0;
                int j = 0;
                for (; j + 16 <= nn; j += 16) {        // 16 edges: 2 loads in flight
                    int sa = __shfl(idx, j + g);
                    int sb = __shfl(idx, j + 8 + g);
                    uint4 ua = xsb[(size_t)sa * 8 + c];
                    uint4 ub = xsb[(size_t)sb * 8 + c];
                    f0[0] += bflo(ua.x); f0[1] += bfhi(ua.x); f0[2] += bflo(ua.y); f0[3] += bfhi(ua.y);
                    f0[4] += bflo(ua.z); f0[5] += bfhi(ua.z); f0[6] += bflo(ua.w); f0[7] += bfhi(ua.w);
                    f1[0] += bflo(ub.x); f1[1] += bfhi(ub.x); f1[2] += bflo(ub.y); f1[3] += bfhi(ub.y);
                    f1[4] += bflo(ub.z); f1[5] += bfhi(ub.z); f1[6] += bflo(ub.w); f1[7] += bfhi(ub.w);
                }
                for (; j < nn; j += 8) {               // tail, 8-wide predicated
                    int rem = nn - j;
                    int sa = __shfl(idx, j + g);
                    if (g < rem) {
                        uint4 ua = xsb[(size_t)sa * 8 + c];
                        f0[0] += bflo(ua.x); f0[1] += bfhi(ua.x); f0[2] += bflo(ua.y); f0[3] += bfhi(ua.y);
                        f0[4] += bflo(ua.z); f0[5] += bfhi(ua.z); f0[6] += bflo(ua.w); f0[7] += bfhi(ua.w);
                    }
                }
            }
            #pragma unroll
            for (int k = 0; k < 8; k++) f0[k] += f1[k];
            #pragma unroll
            for (int m = 8; m < 64; m <<= 1) {         // combine the 8 g-slots
                #pragma unroll
                for (int k = 0; k < 8; k++) f0[k] += __shfl_xor(f0[k], m);
            }
            r.x = bfpack2(f0[0] * dd, f0[1] * dd);
            r.y = bfpack2(f0[2] * dd, f0[3] * dd);
            r.z = bfpack2(f0[4] * dd, f0[5] * dd);
            r.w = bfpack2(f0[6] * dd, f0[7] * dd);
        }
        if (g == 0) sA[w * 16 * SA_STRIDE + i * SA_STRIDE + c] = r;  // 128 B row
    }
    __syncthreads();   // covers sW1t staging AND sA visibility for Phase B

    // ---- Phase B: MFMA MLP (A-fragments from sA; layout identical to old aggb)
    int col = lane & 15;
    int quad = lane >> 4;
    const short8* arow = (const short8*)&sA[w * 16 * SA_STRIDE + col * SA_STRIDE];
    short8 a0 = arow[quad];                    // k = quad*8 + j,      K 0..31
    short8 a1 = arow[4 + quad];                // k = 32 + quad*8 + j, K 32..63

    float zpart[4] = {0, 0, 0, 0};
    #pragma unroll
    for (int h0 = 0; h0 < 8; h0++) {           // 8 hidden tiles of 16
        int hid = h0 * 16 + col;
        const short8* brow = (const short8*)(sW1t + hid * W1TS);
        short8 b0 = brow[quad];                // B[k=quad*8+j][n=col] via W1t rows
        short8 b1f = brow[4 + quad];
        f32x4 cc = {0.f, 0.f, 0.f, 0.f};
        cc = __builtin_amdgcn_mfma_f32_16x16x32_bf16(a0, b0, cc, 0, 0, 0);
        cc = __builtin_amdgcn_mfma_f32_16x16x32_bf16(a1, b1f, cc, 0, 0, 0);
        float bb = sb1[hid], ww = sW2[hid];
        #pragma unroll
        for (int r = 0; r < 4; r++) {          // lane holds rows quad*4+r, col hid
            float v = cc[r] + bb;
            zpart[r] += (v > 0.f ? v : 0.f) * ww;
        }
    }
    #pragma unroll
    for (int m = 1; m < 16; m <<= 1) {         // reduce over the 16 hid columns
        #pragma unroll
        for (int r = 0; r < 4; r++) zpart[r] += __shfl_xor(zpart[r], m);
    }
    if (col == 0) {
        #pragma unroll
        for (int r = 0; r < 4; r++) {
            int n = nbase + quad * 4 + r;
            if (n < n_nodes) zd[n] = zpart[r] * dinv[n];   // pre-scaled for layer 2
        }
    }
}

// ---------- layer-2 aggregation: 8 lanes per node ----------
__global__ __launch_bounds__(1024, 8) void k_gather1(const int* __restrict__ off,
                                                     const int* __restrict__ nend,
                                                     const int* __restrict__ csr,
                                                     const float* __restrict__ zd,
                                                     const float* __restrict__ dinv,
                                                     const float* __restrict__ b2,
                                                     float* __restrict__ out, int n_nodes) {
    int tid = blockIdx.x * 1024 + threadIdx.x;
    int n = tid >> 3;
    int l = tid & 7;
    if (n >= n_nodes) return;
    int beg = off[n], fin = nend[n];
    float a0 = 0.0f, a1 = 0.0f;
    for (int i = beg + l; i < fin; i += 16) {
        a0 += zd[csr[i]];
        int i2 = i + 8;
        if (i2 < fin) a1 += zd[csr[i2]];
    }
    float a = a0 + a1;
    a += __shfl_xor(a, 1);
    a += __shfl_xor(a, 2);
    a += __shfl_xor(a, 4);
    if (l == 0) out[n] = (a + zd[n]) * dinv[n] + b2[0];
}

extern "C" void kernel_launch(void* const* d_in, const int* in_sizes, int n_in,
                              void* d_out, int out_size, void* d_ws, size_t ws_size,
                              hipStream_t stream) {
    const float* x  = (const float*)d_in[0];
    const int*   ei = (const int*)d_in[1];     // [2, E] int32
    const float* W1 = (const float*)d_in[2];
    const float* b1 = (const float*)d_in[3];
    const float* W2 = (const float*)d_in[4];
    const float* b2 = (const float*)d_in[5];
    float* out = (float*)d_out;

    const int N = NNODES;
    const int E = NEDGES;
    const int* src = ei;
    const int* dst = ei + E;

    // workspace (~27 MB):
    // gbcur | off | nend | dinv | zd | csr[NBUK*BUKCAP] | xsb(bf16) | ebuf
    int* gbcur = (int*)d_ws;                   // [NBUK] (padded to 512)
    int* off   = gbcur + 512;                  // [N]
    int* nend  = off + N;                      // [N]
    float* dinv = (float*)(nend + N);          // [N]
    float* zd   = dinv + N;                    // [N]
    int* csr    = (int*)(zd + N);              // [NBUK*BUKCAP] gapped (7.2 MB)
    size_t o1 = ((size_t)((char*)(csr + NBUK * BUKCAP) - (char*)d_ws) + 127) & ~(size_t)127;
    unsigned* xsb = (unsigned*)((char*)d_ws + o1);        // [N*32] = 12.8 MB
    size_t o2 = o1 + (size_t)N * 128;
    int*   ebuf = (int*)((char*)d_ws + o2);               // [NBUK*BUKCAP] 7.2 MB
                                                          // (dies after k_bfill)

    hipMemsetAsync(gbcur, 0, 512 * sizeof(int), stream);
    k_part<<<(E + CHUNK - 1) / CHUNK, 1024, 0, stream>>>(src, dst, gbcur, ebuf, E);
    k_bfill<<<NBUK, 1024, 0, stream>>>(gbcur, ebuf, x, off, nend, dinv, csr, xsb, N);
    k_gmlp<<<(N + TILE_N - 1) / TILE_N, 512, 0, stream>>>(off, nend, csr, (const uint4*)xsb,
                                                          dinv, W1, b1, W2, zd, N);
    k_gather1<<<(N * 8 + 1023) / 1024, 1024, 0, stream>>>(off, nend, csr, zd, dinv, b2, out, N);
}